// Round 2
// 209.331 us; speedup vs baseline: 1.3780x; 1.3780x over previous
//
#include <hip/hip_runtime.h>

#define C_CH 173
#define L_IN 400
#define EPSV 1e-5f
#define KFEAT 55360  // C*32*10

typedef __fp16   fp16x2 __attribute__((ext_vector_type(2)));
typedef _Float16 f16x8  __attribute__((ext_vector_type(8)));
typedef float    f32x4  __attribute__((ext_vector_type(4)));
typedef float    f32x16 __attribute__((ext_vector_type(16)));

// y1T row: 16 g-values (8 dwords) + 1 pad dword. Odd dword stride (9) ->
// conv2 reads (lane stride 9 dwords) and conv1 writes are <=2-way (free).
// 8B alignment lost -> access via b32 pairs (ds_read2/write2_b32).
#define Y1T_STRIDE_I 9
#define Y1T_ROWS   406  // row r = y1 time t+3; rows 0..2, 403..405 zeroed halo

// segmax: [f][sub], sub = 0..99 (100 subsegs of 4 times). Stride 102 f16
// = 51 dwords (odd -> conflict-free per-f rows, gcd(51,32)=1).
// R1 BUG FIX: stride was 98 (<100) -> subs 98,99 overwrote neighbor f's
// subs 0,1 => absmax 9.4e-2. Must be >=100.
#define SEG_STRIDE 102

#define N1 (173 * 3584)  // w2T elems
#define N2 (173 * 512)   // w1T elems
#define N3 (173 * 96)    // BN consts per c: s1[16] sh1[16] s2[32] sh2[32]

// ---------------------------------------------------------------------------
// Prep kernel: materialize per-channel weight layouts + BN consts once.
//  w2T_g[c][dt*512 + f*16 + g] f16 ; w1T_g[c][g*32+k] f16 (k>=9 zero)
//  sc_g[c*96 + r]: r<16 scale1 | r<32 shift1 | r<64 scale2 | r<96 shift2
// ---------------------------------------------------------------------------
__global__ __launch_bounds__(256) void prep_kernel(
    const float* __restrict__ w1, const float* __restrict__ b1,
    const float* __restrict__ g1, const float* __restrict__ beta1,
    const float* __restrict__ m1, const float* __restrict__ v1,
    const float* __restrict__ w2, const float* __restrict__ b2,
    const float* __restrict__ g2, const float* __restrict__ beta2,
    const float* __restrict__ m2, const float* __restrict__ v2,
    _Float16* __restrict__ w2T_g, _Float16* __restrict__ w1T_g,
    float* __restrict__ sc_g)
{
    const int idx = blockIdx.x * 256 + threadIdx.x;
    if (idx < N1) {
        int c = idx / 3584, r = idx - c * 3584;
        int dt = r >> 9, fg = r & 511;
        int f = fg >> 4, g = fg & 15;
        w2T_g[idx] = (_Float16)w2[c * 3584 + f * 112 + g * 7 + dt];
    } else if (idx < N1 + N2) {
        int j = idx - N1;
        int c = j / 512, r = j - c * 512;
        int g = r >> 5, k = r & 31;
        w1T_g[j] = (k < 9) ? (_Float16)w1[c * 144 + g * 9 + k] : (_Float16)0.0f;
    } else if (idx < N1 + N2 + N3) {
        int j = idx - N1 - N2;
        int c = j / 96, r = j - c * 96;
        float o;
        if (r < 32) {
            int g  = r & 15;
            int cf = c * 16 + g;
            float inv = g1[cf] * rsqrtf(v1[cf] + EPSV);
            o = (r < 16) ? inv : (b1[cf] - m1[cf]) * inv + beta1[cf];
        } else {
            int f  = (r - 32) & 31;
            int cf = c * 32 + f;
            float inv = g2[cf] * rsqrtf(v2[cf] + EPSV);
            o = (r < 64) ? inv : (b2[cf] - m2[cf]) * inv + beta2[cf];
        }
        sc_g[j] = o;
    }
}

// ---------------------------------------------------------------------------
// Tower kernel: one block per (c, batch-group of 4). 320 threads = 5 waves.
//  conv2 MFMA operands SWAPPED vs R9: A=y1 (time on row/reg axis), B=w2
//  (f on lane axis). Identical LDS reads, but the 8-wide pool reduction is
//  now a per-lane register tree (16 mul + 12 max + 4 f16 stores) instead of
//  128 VALU ops of redundant DPP cross-lane work per tile.
//  Shift+ReLU deferred to pool stage: relu(max(s2*v) + sh2).
// LDS ~31.5 KB -> 5 blocks/CU (was 43 KB -> 3). VGPR pinned <=64 via
// __launch_bounds__(320,8). af/a1 fragments re-loaded per batch on purpose.
// ---------------------------------------------------------------------------
__global__ __launch_bounds__(320, 8) void tower_kernel(
    const float* __restrict__ x,
    const _Float16* __restrict__ w2T_g, const _Float16* __restrict__ w1T_g,
    const float* __restrict__ sc_g,
    _Float16* __restrict__ featH)
{
    __shared__ __align__(16) _Float16 xa_s[432];             // xa[i] = x_s[i]
    __shared__ __align__(16) _Float16 xb_s[432];             // xb[i] = x_s[i+1]
    __shared__ __align__(16) _Float16 w1T_s[16 * 32];        // [g][k]
    __shared__ __align__(16) _Float16 y1T_s[Y1T_ROWS * 2 * Y1T_STRIDE_I];
    __shared__ __align__(16) _Float16 w2T_s[7 * 512];        // [dt][f][g]
    __shared__ _Float16               segmax_s[32 * SEG_STRIDE]; // [f][sub]
    __shared__ __align__(16) float    cst_s[96];  // s1[16] sh1[16] s2[32] sh2[32]

    const int c   = blockIdx.x;
    const int tid = threadIdx.x;

    // ---- once-per-block staging (coalesced, no div/cvt/scatter) ----
    {
        const int4* w2src = (const int4*)(w2T_g + (size_t)c * 3584);
        for (int i = tid; i < 448; i += 320) ((int4*)w2T_s)[i] = w2src[i];
        const int4* w1src = (const int4*)(w1T_g + c * 512);
        if (tid < 64) ((int4*)w1T_s)[tid] = w1src[tid];
        const float4* csrc = (const float4*)(sc_g + c * 96);
        if (tid >= 64 && tid < 88) ((float4*)cst_s)[tid - 64] = csrc[tid - 64];
        // zero y1T halo rows 0..2 and 403..405 (6 rows x 9 dwords)
        if (tid >= 88 && tid < 142) {
            int i = tid - 88;
            int r = i / 9, cx = i - r * 9;
            int row = (r < 3) ? r : (400 + r);
            ((int*)y1T_s)[row * Y1T_STRIDE_I + cx] = 0;
        }
    }
    __syncthreads();
    // per-lane BN consts for conv2/pool (f = tid&31 in both scopes)
    const float s2f  = cst_s[32 + (tid & 31)];
    const float sh2f = cst_s[64 + (tid & 31)];

    for (int nb = 0; nb < 4; ++nb) {
        const int b = blockIdx.y * 4 + nb;

        // ---- stage x as f16 parity copies ----
        const float* xrow = x + ((size_t)b * C_CH + c) * L_IN;
        for (int i = tid; i < 432; i += 320) {
            float v = (i >= 4 && i < 404) ? xrow[i - 4] : 0.0f;
            _Float16 h = (_Float16)v;
            xa_s[i] = h;
            if (i > 0) xb_s[i - 1] = h;
        }
        if (tid == 0) xb_s[431] = (_Float16)0.0f;
        __syncthreads();

        // ---- conv1 via mfma_16x16x32_f16 -> y1T ----
        // A[m=g][k]=w1T; B[k][n]=x_s[t0+n+k-4] (+4 shift folded into x_s).
        {
            const int lane = tid & 63;
            const int wv5  = tid >> 6;
            const int nl   = lane & 15;
            const int q    = lane >> 4;
            union { int4 v; f16x8 h; } a1;
            a1.v = *(const int4*)((const int*)w1T_s + nl * 16 + q * 4);
            float s1r[4], sh1r[4];
#pragma unroll
            for (int r = 0; r < 4; ++r) {
                s1r[r]  = cst_s[q * 4 + r];
                sh1r[r] = cst_s[16 + q * 4 + r];
            }
            const int* xsel = (const int*)((nl & 1) ? xb_s : xa_s);
            for (int tile = 0; tile < 5; ++tile) {
                const int t0 = (wv5 * 5 + tile) * 16;
                const int dw = (t0 + nl + q * 8) >> 1;
                union { int4 v; f16x8 h; } bf;
                bf.v.x = xsel[dw];
                bf.v.y = xsel[dw + 1];
                bf.v.z = xsel[dw + 2];
                bf.v.w = xsel[dw + 3];
                f32x4 acc = {0.0f, 0.0f, 0.0f, 0.0f};
                acc = __builtin_amdgcn_mfma_f32_16x16x32_f16(a1.h, bf.h, acc, 0, 0, 0);
                union { _Float16 h[4]; int2 d; } pk;
#pragma unroll
                for (int r = 0; r < 4; ++r) {
                    float v = acc[r] * s1r[r] + sh1r[r];
                    pk.h[r] = (_Float16)(v > 0.0f ? v : 0.0f);
                }
                // stride-9 rows are only 4B aligned: two b32 stores
                // (compiler merges to ds_write2_b32)
                int* yp = (int*)y1T_s + (t0 + nl + 3) * Y1T_STRIDE_I + q * 2;
                yp[0] = pk.d.x;
                yp[1] = pk.d.y;
            }
        }
        __syncthreads();

        // ---- conv2 MFMA (swapped operands) + scaled per-lane subseg max ----
        // acc = D[t][f]: f = lane&31, t = t0 + (reg&3) + 8*(reg>>2) + 4*half.
        // Subseg (4 times) = one reg quad; sub = tile*8 + 2q + half.
        {
            const int wv    = tid >> 6;
            const int lane  = tid & 63;
            const int nlane = lane & 31;
            const int half  = lane >> 5;

            union F8q { int4 q; f16x8 h; } af[7];
#pragma unroll
            for (int dt = 0; dt < 7; ++dt)
                af[dt].q = *(const int4*)((const int*)w2T_s + dt * 256 + nlane * 8 + half * 4);

            for (int tile = wv; tile < 13; tile += 5) {
                const int tA  = tile * 32 + nlane;        // A-row time (lane)
                const int tAr = tA < 400 ? tA : 399;      // clamp; bad rows -> discarded regs
                f32x16 acc;
#pragma unroll
                for (int i = 0; i < 16; ++i) acc[i] = 0.0f;

#pragma unroll
                for (int dt = 0; dt < 7; ++dt) {
                    const int* p = (const int*)y1T_s + (tAr + dt) * Y1T_STRIDE_I + half * 4;
                    union { int d[4]; f16x8 h; } bf;
                    bf.d[0] = p[0];
                    bf.d[1] = p[1];
                    bf.d[2] = p[2];
                    bf.d[3] = p[3];
                    acc = __builtin_amdgcn_mfma_f32_32x32x16_f16(bf.h, af[dt].h, acc, 0, 0, 0);
                }

                const int base = nlane * SEG_STRIDE + tile * 8 + half;
#pragma unroll
                for (int q = 0; q < 4; ++q) {
                    // scale per element (sign-safe wrt g2), defer shift+relu
                    float v0 = acc[4 * q + 0] * s2f;
                    float v1 = acc[4 * q + 1] * s2f;
                    float v2 = acc[4 * q + 2] * s2f;
                    float v3 = acc[4 * q + 3] * s2f;
                    float m  = fmaxf(fmaxf(v0, v1), fmaxf(v2, v3));
                    const int sub = tile * 8 + 2 * q + half;
                    if (sub < 100) segmax_s[base + 2 * q] = (_Float16)m;
                }
            }
        }
        __syncthreads();

        // ---- pool(40) = max of 10 subseg-maxes; apply shift + relu ----
        {
            const int f = tid & 31;
            const int p = tid >> 5;
            float m = -3.0e38f;
#pragma unroll
            for (int k = 0; k < 10; ++k)
                m = fmaxf(m, (float)segmax_s[f * SEG_STRIDE + p * 10 + k]);
            float v = fmaxf(m + sh2f, 0.0f);
            featH[(size_t)b * KFEAT + (c * 32 + f) * 10 + p] = (_Float16)v;
        }
        // no trailing sync needed: next iter's x-stage touches xa/xb only;
        // segmax(i) is fully consumed before any wave passes the next
        // post-stage sync; y1T rewritten only after the post-stage sync.
    }
}

// ---------------------------------------------------------------------------
// FC1 f16 MFMA GEMM, split-K without atomics: 173 blocks x KC=320 (20 steps).
// Each block writes a disjoint partial tile part[kb][128][64].
// ---------------------------------------------------------------------------
__global__ __launch_bounds__(256) void fc1_kernel(
    const _Float16* __restrict__ featH, const float* __restrict__ wc1,
    float* __restrict__ part)
{
    const int tid   = threadIdx.x;
    const int kb    = blockIdx.x;
    const int k0    = kb * 320;
    const int lane  = tid & 63;
    const int wv    = tid >> 6;
    const int nlane = lane & 31;
    const int half  = lane >> 5;
    const int jrow  = wv * 32 + nlane;

    const float*    ap  = wc1   + (size_t)jrow * KFEAT + k0 + half * 8;
    const _Float16* b0p = featH + (size_t)nlane * KFEAT + k0 + half * 8;
    const _Float16* b1p = featH + (size_t)(nlane + 32) * KFEAT + k0 + half * 8;

    f32x16 acc0, acc1;
#pragma unroll
    for (int i = 0; i < 16; ++i) { acc0[i] = 0.0f; acc1[i] = 0.0f; }

#pragma unroll 2
    for (int s = 0; s < 20; ++s) {
        const float4 aw0 = *(const float4*)(ap + s * 16);
        const float4 aw1 = *(const float4*)(ap + s * 16 + 4);
        union { fp16x2 v2[4]; f16x8 h; } a;
        a.v2[0] = __builtin_amdgcn_cvt_pkrtz(aw0.x, aw0.y);
        a.v2[1] = __builtin_amdgcn_cvt_pkrtz(aw0.z, aw0.w);
        a.v2[2] = __builtin_amdgcn_cvt_pkrtz(aw1.x, aw1.y);
        a.v2[3] = __builtin_amdgcn_cvt_pkrtz(aw1.z, aw1.w);

        union { int4 q; f16x8 h; } b0, b1;
        b0.q = *(const int4*)(b0p + s * 16);
        b1.q = *(const int4*)(b1p + s * 16);

        acc0 = __builtin_amdgcn_mfma_f32_32x32x16_f16(a.h, b0.h, acc0, 0, 0, 0);
        acc1 = __builtin_amdgcn_mfma_f32_32x32x16_f16(a.h, b1.h, acc1, 0, 0, 0);
    }

    float* pt = part + (size_t)kb * 8192;
#pragma unroll
    for (int reg = 0; reg < 16; ++reg) {
        int j = wv * 32 + (reg & 3) + 8 * (reg >> 2) + 4 * half;
        pt[j * 64 + nlane]      = acc0[reg];
        pt[j * 64 + 32 + nlane] = acc1[reg];
    }
}

// ---------------------------------------------------------------------------
// Reduce partials: h[idx] = sum_kb part[kb][idx]. Coalesced.
// ---------------------------------------------------------------------------
__global__ __launch_bounds__(256) void reduce_kernel(
    const float* __restrict__ part, float* __restrict__ h_ws)
{
    const int idx = blockIdx.x * 256 + threadIdx.x;   // 0..8191
    float s = 0.0f;
    for (int kb = 0; kb < 173; ++kb)
        s += part[(size_t)kb * 8192 + idx];
    h_ws[idx] = s;
}

// ---------------------------------------------------------------------------
// FC2: out[b] = bc2 + sum_j wc2[j] * relu(h[j][b] + bc1[j])
// ---------------------------------------------------------------------------
__global__ __launch_bounds__(64) void fc2_kernel(
    const float* __restrict__ h_ws, const float* __restrict__ bc1,
    const float* __restrict__ wc2, const float* __restrict__ bc2,
    float* __restrict__ out)
{
    const int b = threadIdx.x;
    float acc = bc2[0];
    for (int j = 0; j < 128; ++j) {
        float hv = h_ws[j * 64 + b] + bc1[j];
        hv = hv > 0.0f ? hv : 0.0f;
        acc += wc2[j] * hv;
    }
    out[b] = acc;
}

extern "C" void kernel_launch(void* const* d_in, const int* in_sizes, int n_in,
                              void* d_out, int out_size, void* d_ws, size_t ws_size,
                              hipStream_t stream)
{
    const float* x     = (const float*)d_in[0];
    const float* w1    = (const float*)d_in[1];
    const float* b1    = (const float*)d_in[2];
    const float* g1    = (const float*)d_in[3];
    const float* beta1 = (const float*)d_in[4];
    const float* m1    = (const float*)d_in[5];
    const float* v1    = (const float*)d_in[6];
    const float* w2    = (const float*)d_in[7];
    const float* b2    = (const float*)d_in[8];
    const float* g2    = (const float*)d_in[9];
    const float* beta2 = (const float*)d_in[10];
    const float* m2    = (const float*)d_in[11];
    const float* v2    = (const float*)d_in[12];
    const float* wc1   = (const float*)d_in[13];
    const float* bc1   = (const float*)d_in[14];
    const float* wc2   = (const float*)d_in[15];
    const float* bc2   = (const float*)d_in[16];

    char* ws = (char*)d_ws;
    _Float16* featH = (_Float16*)ws;                          // 7,086,080 B
    float*    part  = (float*)(ws + 7086080);                 // 5,668,864 B
    float*    h_ws  = (float*)(ws + 12754944);                // 32,768 B
    _Float16* w2T_g = (_Float16*)(ws + 12787712);             // 1,240,064 B
    _Float16* w1T_g = (_Float16*)(ws + 14027776);             // 177,152 B
    float*    sc_g  = (float*)(ws + 14204928);                // 66,432 B

    hipLaunchKernelGGL(prep_kernel, dim3(2834), dim3(256), 0, stream,
                       w1, b1, g1, beta1, m1, v1,
                       w2, b2, g2, beta2, m2, v2, w2T_g, w1T_g, sc_g);

    hipLaunchKernelGGL(tower_kernel, dim3(C_CH, 16), dim3(320), 0, stream,
                       x, w2T_g, w1T_g, sc_g, featH);

    hipLaunchKernelGGL(fc1_kernel, dim3(173), dim3(256), 0, stream,
                       featH, wc1, part);

    hipLaunchKernelGGL(reduce_kernel, dim3(32), dim3(256), 0, stream,
                       part, h_ws);

    hipLaunchKernelGGL(fc2_kernel, dim3(1), dim3(64), 0, stream,
                       h_ws, bc1, wc2, bc2, (float*)d_out);
}

// Round 3
// 209.119 us; speedup vs baseline: 1.3794x; 1.0010x over previous
//
#include <hip/hip_runtime.h>

#define C_CH 173
#define L_IN 400
#define EPSV 1e-5f
#define KFEAT 55360  // C*32*10

typedef __fp16   fp16x2 __attribute__((ext_vector_type(2)));
typedef _Float16 f16x8  __attribute__((ext_vector_type(8)));
typedef float    f32x4  __attribute__((ext_vector_type(4)));
typedef float    f32x16 __attribute__((ext_vector_type(16)));

// y1T row: 16 g-values (8 dwords) + 1 pad dword. Odd dword stride (9) ->
// conv2 reads (lane stride 9 dwords) and conv1 writes are <=2-way (free).
// 8B alignment lost -> access via b32 pairs (ds_read2/write2_b32).
#define Y1T_STRIDE_I 9
#define Y1T_ROWS   406  // row r = y1 time t+3; rows 0..2, 403..405 zeroed halo

// segmax: [f][sub], sub = 0..99 (100 subsegs of 4 times). Stride 102 f16
// = 51 dwords (odd -> conflict-free per-f rows, gcd(51,32)=1). Must be >=100.
#define SEG_STRIDE 102

#define N1 (173 * 3584)  // w2T elems
#define N2 (173 * 512)   // w1T elems
#define N3 (173 * 96)    // BN consts per c: s1[16] sh1[16] s2[32] sh2[32]

// ---------------------------------------------------------------------------
// Prep kernel: materialize per-channel weight layouts + BN consts once.
//  w2T_g[c][dt*512 + f*16 + g] f16 ; w1T_g[c][g*32+k] f16 (k>=9 zero)
//  sc_g[c*96 + r]: r<16 scale1 | r<32 shift1 | r<64 scale2 | r<96 shift2
// ---------------------------------------------------------------------------
__global__ __launch_bounds__(256) void prep_kernel(
    const float* __restrict__ w1, const float* __restrict__ b1,
    const float* __restrict__ g1, const float* __restrict__ beta1,
    const float* __restrict__ m1, const float* __restrict__ v1,
    const float* __restrict__ w2, const float* __restrict__ b2,
    const float* __restrict__ g2, const float* __restrict__ beta2,
    const float* __restrict__ m2, const float* __restrict__ v2,
    _Float16* __restrict__ w2T_g, _Float16* __restrict__ w1T_g,
    float* __restrict__ sc_g)
{
    const int idx = blockIdx.x * 256 + threadIdx.x;
    if (idx < N1) {
        int c = idx / 3584, r = idx - c * 3584;
        int dt = r >> 9, fg = r & 511;
        int f = fg >> 4, g = fg & 15;
        w2T_g[idx] = (_Float16)w2[c * 3584 + f * 112 + g * 7 + dt];
    } else if (idx < N1 + N2) {
        int j = idx - N1;
        int c = j / 512, r = j - c * 512;
        int g = r >> 5, k = r & 31;
        w1T_g[j] = (k < 9) ? (_Float16)w1[c * 144 + g * 9 + k] : (_Float16)0.0f;
    } else if (idx < N1 + N2 + N3) {
        int j = idx - N1 - N2;
        int c = j / 96, r = j - c * 96;
        float o;
        if (r < 32) {
            int g  = r & 15;
            int cf = c * 16 + g;
            float inv = g1[cf] * rsqrtf(v1[cf] + EPSV);
            o = (r < 16) ? inv : (b1[cf] - m1[cf]) * inv + beta1[cf];
        } else {
            int f  = (r - 32) & 31;
            int cf = c * 32 + f;
            float inv = g2[cf] * rsqrtf(v2[cf] + EPSV);
            o = (r < 64) ? inv : (b2[cf] - m2[cf]) * inv + beta2[cf];
        }
        sc_g[j] = o;
    }
}

// ---------------------------------------------------------------------------
// Tower kernel: one block per (c, batch-group of 4). 320 threads = 5 waves.
//  conv2: A=y1 (time on row/reg axis), B=w2 (f on lane axis) -> per-lane
//  register pool reduction. Shift+ReLU deferred to pool: relu(max(s2*v)+sh2).
//  R3: af[7] (w2 fragments) hoisted out of the batch loop — the ds_read_b128
//  at dword-stride 8 is 4-way bank-conflicted (banks {0,8,16,24}); paying it
//  once per block instead of 4x removes ~75% of SQ_LDS_BANK_CONFLICT.
//  VGPR rises ~44->72; occupancy stays LDS-bound at 5 blocks/CU (25 waves/CU
//  = 6.25 waves/SIMD), so __launch_bounds__(320,7) (budget 73 VGPR) keeps it.
// LDS 31744 B -> 5 blocks/CU.
// ---------------------------------------------------------------------------
__global__ __launch_bounds__(320, 7) void tower_kernel(
    const float* __restrict__ x,
    const _Float16* __restrict__ w2T_g, const _Float16* __restrict__ w1T_g,
    const float* __restrict__ sc_g,
    _Float16* __restrict__ featH)
{
    __shared__ __align__(16) _Float16 xa_s[432];             // xa[i] = x_s[i]
    __shared__ __align__(16) _Float16 xb_s[432];             // xb[i] = x_s[i+1]
    __shared__ __align__(16) _Float16 w1T_s[16 * 32];        // [g][k]
    __shared__ __align__(16) _Float16 y1T_s[Y1T_ROWS * 2 * Y1T_STRIDE_I];
    __shared__ __align__(16) _Float16 w2T_s[7 * 512];        // [dt][f][g]
    __shared__ _Float16               segmax_s[32 * SEG_STRIDE]; // [f][sub]
    __shared__ __align__(16) float    cst_s[96];  // s1[16] sh1[16] s2[32] sh2[32]

    const int c   = blockIdx.x;
    const int tid = threadIdx.x;

    // ---- once-per-block staging (coalesced, no div/cvt/scatter) ----
    {
        const int4* w2src = (const int4*)(w2T_g + (size_t)c * 3584);
        for (int i = tid; i < 448; i += 320) ((int4*)w2T_s)[i] = w2src[i];
        const int4* w1src = (const int4*)(w1T_g + c * 512);
        if (tid < 64) ((int4*)w1T_s)[tid] = w1src[tid];
        const float4* csrc = (const float4*)(sc_g + c * 96);
        if (tid >= 64 && tid < 88) ((float4*)cst_s)[tid - 64] = csrc[tid - 64];
        // zero y1T halo rows 0..2 and 403..405 (6 rows x 9 dwords)
        if (tid >= 88 && tid < 142) {
            int i = tid - 88;
            int r = i / 9, cx = i - r * 9;
            int row = (r < 3) ? r : (400 + r);
            ((int*)y1T_s)[row * Y1T_STRIDE_I + cx] = 0;
        }
    }
    __syncthreads();
    // per-lane BN consts for conv2/pool (f = tid&31 in both scopes)
    const float s2f  = cst_s[32 + (tid & 31)];
    const float sh2f = cst_s[64 + (tid & 31)];

    // ---- hoisted conv2 weight fragments (loop-invariant across batches) ----
    const int nlaneH = tid & 31;
    const int halfH  = (tid >> 5) & 1;
    union F8q { int4 q; f16x8 h; } af[7];
#pragma unroll
    for (int dt = 0; dt < 7; ++dt)
        af[dt].q = *(const int4*)((const int*)w2T_s + dt * 256 + nlaneH * 8 + halfH * 4);

    for (int nb = 0; nb < 4; ++nb) {
        const int b = blockIdx.y * 4 + nb;

        // ---- stage x as f16 parity copies ----
        const float* xrow = x + ((size_t)b * C_CH + c) * L_IN;
        for (int i = tid; i < 432; i += 320) {
            float v = (i >= 4 && i < 404) ? xrow[i - 4] : 0.0f;
            _Float16 h = (_Float16)v;
            xa_s[i] = h;
            if (i > 0) xb_s[i - 1] = h;
        }
        if (tid == 0) xb_s[431] = (_Float16)0.0f;
        __syncthreads();

        // ---- conv1 via mfma_16x16x32_f16 -> y1T ----
        // A[m=g][k]=w1T; B[k][n]=x_s[t0+n+k-4] (+4 shift folded into x_s).
        {
            const int lane = tid & 63;
            const int wv5  = tid >> 6;
            const int nl   = lane & 15;
            const int q    = lane >> 4;
            union { int4 v; f16x8 h; } a1;
            a1.v = *(const int4*)((const int*)w1T_s + nl * 16 + q * 4);
            float s1r[4], sh1r[4];
#pragma unroll
            for (int r = 0; r < 4; ++r) {
                s1r[r]  = cst_s[q * 4 + r];
                sh1r[r] = cst_s[16 + q * 4 + r];
            }
            const int* xsel = (const int*)((nl & 1) ? xb_s : xa_s);
            for (int tile = 0; tile < 5; ++tile) {
                const int t0 = (wv5 * 5 + tile) * 16;
                const int dw = (t0 + nl + q * 8) >> 1;
                union { int4 v; f16x8 h; } bf;
                bf.v.x = xsel[dw];
                bf.v.y = xsel[dw + 1];
                bf.v.z = xsel[dw + 2];
                bf.v.w = xsel[dw + 3];
                f32x4 acc = {0.0f, 0.0f, 0.0f, 0.0f};
                acc = __builtin_amdgcn_mfma_f32_16x16x32_f16(a1.h, bf.h, acc, 0, 0, 0);
                union { _Float16 h[4]; int2 d; } pk;
#pragma unroll
                for (int r = 0; r < 4; ++r) {
                    float v = acc[r] * s1r[r] + sh1r[r];
                    pk.h[r] = (_Float16)(v > 0.0f ? v : 0.0f);
                }
                // stride-9 rows are only 4B aligned: two b32 stores
                int* yp = (int*)y1T_s + (t0 + nl + 3) * Y1T_STRIDE_I + q * 2;
                yp[0] = pk.d.x;
                yp[1] = pk.d.y;
            }
        }
        __syncthreads();

        // ---- conv2 MFMA (swapped operands) + scaled per-lane subseg max ----
        // acc = D[t][f]: f = lane&31, t = t0 + (reg&3) + 8*(reg>>2) + 4*half.
        // Subseg (4 times) = one reg quad; sub = tile*8 + 2q + half.
        {
            const int wv    = tid >> 6;
            const int nlane = nlaneH;
            const int half  = halfH;

            for (int tile = wv; tile < 13; tile += 5) {
                const int tA  = tile * 32 + nlane;        // A-row time (lane)
                const int tAr = tA < 400 ? tA : 399;      // clamp; bad rows -> discarded regs
                f32x16 acc;
#pragma unroll
                for (int i = 0; i < 16; ++i) acc[i] = 0.0f;

#pragma unroll
                for (int dt = 0; dt < 7; ++dt) {
                    const int* p = (const int*)y1T_s + (tAr + dt) * Y1T_STRIDE_I + half * 4;
                    union { int d[4]; f16x8 h; } bf;
                    bf.d[0] = p[0];
                    bf.d[1] = p[1];
                    bf.d[2] = p[2];
                    bf.d[3] = p[3];
                    acc = __builtin_amdgcn_mfma_f32_32x32x16_f16(bf.h, af[dt].h, acc, 0, 0, 0);
                }

                const int base = nlane * SEG_STRIDE + tile * 8 + half;
#pragma unroll
                for (int q = 0; q < 4; ++q) {
                    // scale per element (sign-safe wrt g2), defer shift+relu
                    float v0 = acc[4 * q + 0] * s2f;
                    float v1 = acc[4 * q + 1] * s2f;
                    float v2 = acc[4 * q + 2] * s2f;
                    float v3 = acc[4 * q + 3] * s2f;
                    float m  = fmaxf(fmaxf(v0, v1), fmaxf(v2, v3));
                    const int sub = tile * 8 + 2 * q + half;
                    if (sub < 100) segmax_s[base + 2 * q] = (_Float16)m;
                }
            }
        }
        __syncthreads();

        // ---- pool(40) = max of 10 subseg-maxes; apply shift + relu ----
        {
            const int f = tid & 31;
            const int p = tid >> 5;
            float m = -3.0e38f;
#pragma unroll
            for (int k = 0; k < 10; ++k)
                m = fmaxf(m, (float)segmax_s[f * SEG_STRIDE + p * 10 + k]);
            float v = fmaxf(m + sh2f, 0.0f);
            featH[(size_t)b * KFEAT + (c * 32 + f) * 10 + p] = (_Float16)v;
        }
        // no trailing sync needed: next iter's x-stage touches xa/xb only;
        // segmax(i) is fully consumed before any wave passes the next
        // post-stage sync; y1T rewritten only after the post-stage sync.
    }
}

// ---------------------------------------------------------------------------
// FC1 f16 MFMA GEMM, split-K without atomics: 173 blocks x KC=320 (20 steps).
// Each block writes a disjoint partial tile part[kb][128][64].
// R3: unroll 4 (was 2) — 173 blocks = ~1 wave/SIMD, latency hiding must come
// from ILP; 4-deep keeps ~16 VMEM loads in flight.
// ---------------------------------------------------------------------------
__global__ __launch_bounds__(256) void fc1_kernel(
    const _Float16* __restrict__ featH, const float* __restrict__ wc1,
    float* __restrict__ part)
{
    const int tid   = threadIdx.x;
    const int kb    = blockIdx.x;
    const int k0    = kb * 320;
    const int lane  = tid & 63;
    const int wv    = tid >> 6;
    const int nlane = lane & 31;
    const int half  = lane >> 5;
    const int jrow  = wv * 32 + nlane;

    const float*    ap  = wc1   + (size_t)jrow * KFEAT + k0 + half * 8;
    const _Float16* b0p = featH + (size_t)nlane * KFEAT + k0 + half * 8;
    const _Float16* b1p = featH + (size_t)(nlane + 32) * KFEAT + k0 + half * 8;

    f32x16 acc0, acc1;
#pragma unroll
    for (int i = 0; i < 16; ++i) { acc0[i] = 0.0f; acc1[i] = 0.0f; }

#pragma unroll 4
    for (int s = 0; s < 20; ++s) {
        const float4 aw0 = *(const float4*)(ap + s * 16);
        const float4 aw1 = *(const float4*)(ap + s * 16 + 4);
        union { fp16x2 v2[4]; f16x8 h; } a;
        a.v2[0] = __builtin_amdgcn_cvt_pkrtz(aw0.x, aw0.y);
        a.v2[1] = __builtin_amdgcn_cvt_pkrtz(aw0.z, aw0.w);
        a.v2[2] = __builtin_amdgcn_cvt_pkrtz(aw1.x, aw1.y);
        a.v2[3] = __builtin_amdgcn_cvt_pkrtz(aw1.z, aw1.w);

        union { int4 q; f16x8 h; } b0, b1;
        b0.q = *(const int4*)(b0p + s * 16);
        b1.q = *(const int4*)(b1p + s * 16);

        acc0 = __builtin_amdgcn_mfma_f32_32x32x16_f16(a.h, b0.h, acc0, 0, 0, 0);
        acc1 = __builtin_amdgcn_mfma_f32_32x32x16_f16(a.h, b1.h, acc1, 0, 0, 0);
    }

    float* pt = part + (size_t)kb * 8192;
#pragma unroll
    for (int reg = 0; reg < 16; ++reg) {
        int j = wv * 32 + (reg & 3) + 8 * (reg >> 2) + 4 * half;
        pt[j * 64 + nlane]      = acc0[reg];
        pt[j * 64 + 32 + nlane] = acc1[reg];
    }
}

// ---------------------------------------------------------------------------
// Fused reduce + FC2 (R3: was two kernels; single-block fc2 was pure latency).
// Grid 64 blocks (one per batch b) x 256 threads.
//  thread t: j = t>>1, khalf = t&1 -> partial sum over ~86 kb planes
//  LDS combine -> relu(h+bc1)*wc2 -> tree+shuffle reduce -> out[b].
// part reads are 4B-scattered at 256B stride, but part (5.67 MB) is
// L2/L3-resident (just written by fc1); cross-block line reuse via L3.
// ---------------------------------------------------------------------------
__global__ __launch_bounds__(256) void reduce_fc2_kernel(
    const float* __restrict__ part, const float* __restrict__ bc1,
    const float* __restrict__ wc2, const float* __restrict__ bc2,
    float* __restrict__ out)
{
    __shared__ float hsum[256];   // [j][khalf]
    __shared__ float vsum[128];

    const int b = blockIdx.x;
    const int t = threadIdx.x;
    const int j = t >> 1;
    const int kh = t & 1;

    const float* p = part + (size_t)j * 64 + b;
    const int kb0 = kh ? 87 : 0;
    const int kb1 = kh ? 173 : 87;
    float s = 0.0f;
#pragma unroll 4
    for (int kb = kb0; kb < kb1; ++kb)
        s += p[(size_t)kb * 8192];
    hsum[t] = s;
    __syncthreads();

    float v = 0.0f;
    if (t < 128) {
        float h = hsum[t * 2] + hsum[t * 2 + 1] + bc1[t];
        h = h > 0.0f ? h : 0.0f;
        v = wc2[t] * h;
        vsum[t] = v;
    }
    __syncthreads();

    if (t < 64) {
        float r = vsum[t] + vsum[t + 64];
        r += __shfl_down(r, 32);
        r += __shfl_down(r, 16);
        r += __shfl_down(r, 8);
        r += __shfl_down(r, 4);
        r += __shfl_down(r, 2);
        r += __shfl_down(r, 1);
        if (t == 0) out[b] = r + bc2[0];
    }
}

extern "C" void kernel_launch(void* const* d_in, const int* in_sizes, int n_in,
                              void* d_out, int out_size, void* d_ws, size_t ws_size,
                              hipStream_t stream)
{
    const float* x     = (const float*)d_in[0];
    const float* w1    = (const float*)d_in[1];
    const float* b1    = (const float*)d_in[2];
    const float* g1    = (const float*)d_in[3];
    const float* beta1 = (const float*)d_in[4];
    const float* m1    = (const float*)d_in[5];
    const float* v1    = (const float*)d_in[6];
    const float* w2    = (const float*)d_in[7];
    const float* b2    = (const float*)d_in[8];
    const float* g2    = (const float*)d_in[9];
    const float* beta2 = (const float*)d_in[10];
    const float* m2    = (const float*)d_in[11];
    const float* v2    = (const float*)d_in[12];
    const float* wc1   = (const float*)d_in[13];
    const float* bc1   = (const float*)d_in[14];
    const float* wc2   = (const float*)d_in[15];
    const float* bc2   = (const float*)d_in[16];

    char* ws = (char*)d_ws;
    _Float16* featH = (_Float16*)ws;                          // 7,086,080 B
    float*    part  = (float*)(ws + 7086080);                 // 5,668,864 B
    _Float16* w2T_g = (_Float16*)(ws + 12787712);             // 1,240,064 B
    _Float16* w1T_g = (_Float16*)(ws + 14027776);             // 177,152 B
    float*    sc_g  = (float*)(ws + 14204928);                // 66,432 B

    hipLaunchKernelGGL(prep_kernel, dim3(2834), dim3(256), 0, stream,
                       w1, b1, g1, beta1, m1, v1,
                       w2, b2, g2, beta2, m2, v2, w2T_g, w1T_g, sc_g);

    hipLaunchKernelGGL(tower_kernel, dim3(C_CH, 16), dim3(320), 0, stream,
                       x, w2T_g, w1T_g, sc_g, featH);

    hipLaunchKernelGGL(fc1_kernel, dim3(173), dim3(256), 0, stream,
                       featH, wc1, part);

    hipLaunchKernelGGL(reduce_fc2_kernel, dim3(64), dim3(256), 0, stream,
                       part, bc1, wc2, bc2, (float*)d_out);
}